// Round 10
// baseline (341.244 us; speedup 1.0000x reference)
//
#include <hip/hip_runtime.h>
#include <math.h>

// ProbAttention (Informer ProbSparse) — B=8 L=2048 H=8 D=64 u=40
// q/k/v reshape(B,H,L,D) is a flat reinterpretation -> treat as (BH=64, L, D) contiguous.
#define LSEQ 2048
#define DDIM 64
#define UU   40
#define NBH  64
#define NCHUNK 16
#define CROWS  128            // rows per k-chunk (CROWS*NCHUNK == LSEQ)
#define CTX_ELEMS (NBH*UU*DDIM)   // 163840

// 8-lane-group sum via DPP (pure VALU — keeps the LDS pipe free).
__device__ __forceinline__ float grp8_sum(float x) {
  float t;
  t = __int_as_float(__builtin_amdgcn_update_dpp(0, __float_as_int(x), 0xB1, 0xF, 0xF, false));
  x += t;
  t = __int_as_float(__builtin_amdgcn_update_dpp(0, __float_as_int(x), 0x4E, 0xF, 0xF, false));
  x += t;
  t = __int_as_float(__builtin_amdgcn_update_dpp(0, __float_as_int(x), 0x141, 0xF, 0xF, false));
  x += t;
  return x;
}

// ---------------- K0: bin sample indices by 128-row chunk (shared across all bh) ----
// One wave per l. Stable wave-parallel bucket sort via ballot/popcount. [proven R2-R9]
__global__ __launch_bounds__(256) void k0_sort(
    const int* __restrict__ idxs, int* __restrict__ sidx, int* __restrict__ soff) {
  int l = blockIdx.x * 4 + (threadIdx.x >> 6);
  int lane = threadIdx.x & 63;
  int v = 0, c = NCHUNK;              // lanes >= UU get invalid chunk
  if (lane < UU) { v = idxs[l * UU + lane]; c = v >> 7; }   // 128 rows/chunk
  unsigned long long lower = (1ull << lane) - 1ull;
  int base = 0;
#pragma unroll
  for (int cc = 0; cc < NCHUNK; ++cc) {
    unsigned long long m = __ballot(c == cc);
    if (c == cc) {
      int rank = __popcll(m & lower);
      sidx[l * UU + base + rank] = v;
    }
    int cnt = __popcll(m);
    if (lane == cc) soff[l * NCHUNK + cc] = (base << 8) | cnt;
    base += cnt;
  }
}

// ---------------- K12 (R6 form, reverted): LDS-chunk gather, sequential l ----------
// R7-R9 verdict: cnt-sorting saves ~15us issue time but every realization broke the
// lockstep memory locality worth 20-40us (q re-fetch or Mpart RMW). R6's sequential
// sweep is the local optimum: 87us, FETCH 34.7MB, WRITE 18.5MB.
// NOW LAUNCHED AS TWO 512-BLOCK HALVES (boff): visibility instrument — drops the
// top-5 cutoff from ~87 to ~44us so the hidden 204us of non-k12 mass finally shows.
__global__ __launch_bounds__(512, 8) void k12_gather(
    const float* __restrict__ q, const float* __restrict__ k,
    const int* __restrict__ sidx, const int* __restrict__ soff,
    float2* __restrict__ Mpart, int boff) {
  __shared__ float4 kt[CROWS * 16];   // 32KB, linear row-major
  int b = blockIdx.x + boff;
  int bh = b & 63;
  int c  = b >> 6;
  int t  = threadIdx.x;

  {
    const float4* src = (const float4*)(k + ((size_t)bh * LSEQ + c * CROWS) * DDIM);
#pragma unroll
    for (int j = 0; j < 4; ++j) kt[t + 512 * j] = src[t + 512 * j];
  }
  __syncthreads();

  int w = t >> 6;            // wave 0..7 owns l in [w*256, w*256+256)
  int lane = t & 63;
  int g = lane >> 3;         // group 0..7 (one l each per batch)
  int sub = lane & 7;

#pragma unroll 1
  for (int lb = 0; lb < 256; lb += 8) {
    int l = w * 256 + lb + g;
    const float4* qr = (const float4*)(q + ((size_t)bh * LSEQ + l) * DDIM);
    float4 qa = qr[sub];        // q row bytes [0,128)
    float4 qb = qr[sub + 8];    // q row bytes [128,256)
    int oc   = soff[l * NCHUNK + c];
    int cnt  = oc & 255;
    int base = oc >> 8;
    const int* sp = sidx + l * UU + base;    // sidx padded +16 -> safe overread
    int rowv[8];
#pragma unroll
    for (int s = 0; s < 8; ++s) rowv[s] = sp[s] & (CROWS - 1);
    float mx = -INFINITY, sm = 0.f;
#pragma unroll
    for (int s = 0; s < 8; ++s) {
      if (__any(s < cnt)) {                  // wave-uniform skip of dead slots
        if (s < cnt) {
          const float4* kr = kt + rowv[s] * 16;
          float4 a  = kr[sub];
          float4 bq = kr[sub + 8];
          float d = qa.x * a.x + qa.y * a.y + qa.z * a.z + qa.w * a.w
                  + qb.x * bq.x + qb.y * bq.y + qb.z * bq.z + qb.w * bq.w;
          d = grp8_sum(d);                    // group-wide: all 8 lanes active
          mx = fmaxf(mx, d);
          sm += d;
        }
      }
    }
    for (int s = 8; s < cnt; ++s) {           // very rare (P(cnt>8) ~ 5e-4)
      int row = sidx[l * UU + base + s] & (CROWS - 1);
      const float4* kr = kt + row * 16;
      float4 a  = kr[sub];
      float4 bq = kr[sub + 8];
      float d = qa.x * a.x + qa.y * a.y + qa.z * a.z + qa.w * a.w
              + qb.x * bq.x + qb.y * bq.y + qb.z * bq.z + qb.w * bq.w;
      d = grp8_sum(d);
      mx = fmaxf(mx, d);
      sm += d;
    }
    if (sub == 0) Mpart[((size_t)bh * NCHUNK + c) * LSEQ + l] = make_float2(mx, sm);
  }
}

// ---------------- K3: top-40 per head; combines 16 Mpart chunks during load --------
// desc value, tie -> smaller index (matches jax.lax.top_k stability)
__global__ __launch_bounds__(256) void k3_topk(const float2* __restrict__ Mp,
                                               int* __restrict__ Mtop) {
  int bh = blockIdx.x;
  int t = threadIdx.x;
  int w = t >> 6;
  int lane = t & 63;
  float v[8];
#pragma unroll
  for (int j = 0; j < 8; ++j) {
    int l = t + 256 * j;
    float mxv = -INFINITY, smv = 0.f;
#pragma unroll
    for (int c = 0; c < NCHUNK; ++c) {
      float2 p = Mp[((size_t)bh * NCHUNK + c) * LSEQ + l];
      mxv = fmaxf(mxv, p.x);
      smv += p.y;
    }
    v[j] = mxv - smv * (1.0f / (float)LSEQ);
  }
  __shared__ float swv[4];
  __shared__ int   swi[4];
  __shared__ int   win;
  for (int it = 0; it < UU; ++it) {
    float bv = -INFINITY; int bi = 0x7fffffff;
#pragma unroll
    for (int j = 0; j < 8; ++j) {
      if (v[j] > bv) { bv = v[j]; bi = t + 256 * j; }
    }
#pragma unroll
    for (int off = 32; off > 0; off >>= 1) {
      float ov = __shfl_xor(bv, off, 64);
      int   oi = __shfl_xor(bi, off, 64);
      if (ov > bv || (ov == bv && oi < bi)) { bv = ov; bi = oi; }
    }
    if (lane == 0) { swv[w] = bv; swi[w] = bi; }
    __syncthreads();
    if (t == 0) {
      float fv = swv[0]; int fi = swi[0];
#pragma unroll
      for (int j = 1; j < 4; ++j) {
        if (swv[j] > fv || (swv[j] == fv && swi[j] < fi)) { fv = swv[j]; fi = swi[j]; }
      }
      Mtop[bh * UU + it] = fi;
      win = fi;
    }
    __syncthreads();
    int wi = win;
#pragma unroll
    for (int j = 0; j < 8; ++j)
      if (wi == t + 256 * j) v[j] = -INFINITY;   // static index, predicated
  }
}

// ---------------- K457 v2: 8 u per block -> k/v streaming HALVED -------------------
// 320 blocks: bh = b&63, ug = b>>6 (8 u each; 5 blocks/bh instead of 10).
// Arithmetic: phases A+B stream k then v (1MB/block). 10 blocks/bh = 654MB of
// redundant L2/L3 traffic for 64MB of data; 5 blocks/bh = 327MB. LDS = sct 64KB +
// vtile 16KB = 80KB -> 2 blocks/CU. Phase A switches to the k12-proven 8-lane-group
// geometry with DPP reduce (kills 256 shfl/thread of LDS-pipe pressure vs R5 form).
// Softmax: wave w owns rows 2w, 2w+1. Phase B: acc[8] per thread, proven R5 layout.
// ctx fully written at the end — no atomics, no zeroing.
__global__ __launch_bounds__(256, 2) void k457_fused(
    const float* __restrict__ q, const float* __restrict__ k,
    const float* __restrict__ v, const int* __restrict__ Mtop,
    float* __restrict__ attn, float* __restrict__ ctx) {
  __shared__ float  sct[8 * LSEQ];     // 64KB, [u][l]: scores -> normalized attn
  __shared__ float4 vt4[64 * 16];      // 16KB v tile (swizzled); reused as pacc
  int b = blockIdx.x;
  int bh = b & 63;
  int u0 = (b >> 6) * 8;
  int t = threadIdx.x;
  int w = t >> 6, lane = t & 63;

  // ---- phase A: scores, 8-lane-group geometry + DPP (k row read once per 8 u) ----
  {
    int g = t >> 3;          // 0..31: row within 32-row stripe
    int sub = t & 7;
    float4 qa[8], qb[8];
#pragma unroll
    for (int u = 0; u < 8; ++u) {
      int qi = Mtop[bh * UU + u0 + u];
      const float4* qr = (const float4*)(q + (size_t)(bh * LSEQ + qi) * DDIM);
      qa[u] = qr[sub];         // q row bytes [0,128)
      qb[u] = qr[sub + 8];     // bytes [128,256)
    }
    const float* kb = k + (size_t)bh * LSEQ * DDIM;
#pragma unroll 1
    for (int p = 0; p < 64; ++p) {
      int l = p * 32 + g;
      const float4* kr = (const float4*)(kb + (size_t)l * DDIM);
      float4 ka = kr[sub];     // wave reads 8 rows x 256B contiguous -> coalesced
      float4 kc = kr[sub + 8];
#pragma unroll
      for (int u = 0; u < 8; ++u) {
        float s = qa[u].x * ka.x + qa[u].y * ka.y + qa[u].z * ka.z + qa[u].w * ka.w
                + qb[u].x * kc.x + qb[u].y * kc.y + qb[u].z * kc.z + qb[u].w * kc.w;
        s = grp8_sum(s);
        if (sub == 0) sct[u * LSEQ + l] = s * 0.125f;   // banks l%32: conflict-free
      }
    }
  }
  __syncthreads();

  // ---- softmax: wave w owns rows 2w and 2w+1; write normalized to sct AND attn ----
#pragma unroll 1
  for (int uu = w * 2; uu < w * 2 + 2; ++uu) {
    float* row = sct + uu * LSEQ;
    float vv[32];
    float mx = -INFINITY;
#pragma unroll
    for (int j = 0; j < 32; ++j) { vv[j] = row[lane + 64 * j]; mx = fmaxf(mx, vv[j]); }
#pragma unroll
    for (int off = 32; off > 0; off >>= 1) mx = fmaxf(mx, __shfl_xor(mx, off, 64));
    float sm = 0.f;
#pragma unroll
    for (int j = 0; j < 32; ++j) { vv[j] = __expf(vv[j] - mx); sm += vv[j]; }
#pragma unroll
    for (int off = 32; off > 0; off >>= 1) sm += __shfl_xor(sm, off, 64);
    float inv = 1.0f / sm;
    float* ap = attn + (size_t)(bh * UU + u0 + uu) * LSEQ;
#pragma unroll
    for (int j = 0; j < 32; ++j) {
      float a = vv[j] * inv;
      row[lane + 64 * j] = a;
      ap[lane + 64 * j] = a;
    }
  }
  __syncthreads();

  // ---- phase B: ctx[bh, u0+u, :] = sum_l attn[u][l] * v[bh, l, :] ----
  int dq = lane & 15;        // d-quad: d = dq*4 .. dq*4+3
  int lq = lane >> 4;        // row-slice 0..3
  float4 acc[8];
#pragma unroll
  for (int u = 0; u < 8; ++u) acc[u] = make_float4(0.f, 0.f, 0.f, 0.f);

  const float4* vsrc = (const float4*)(v + (size_t)bh * LSEQ * DDIM);
#pragma unroll 1
  for (int tile = 0; tile < 32; ++tile) {
    // stage 64 v rows, float4-slot swizzle: slot = c4 ^ (row&3)   [proven R5]
#pragma unroll
    for (int i = 0; i < 4; ++i) {
      int idx = t + 256 * i;            // float4 index in tile (0..1023)
      int row = idx >> 4, c4 = idx & 15;
      vt4[row * 16 + (c4 ^ (row & 3))] = vsrc[tile * 1024 + idx];
    }
    __syncthreads();
#pragma unroll
    for (int i = 0; i < 4; ++i) {
      int r = w * 16 + i * 4 + lq;      // row in tile; wave w owns rows w*16..+16
      int l = tile * 64 + r;
      float4 vv4 = vt4[r * 16 + (dq ^ (r & 3))];   // 4 lq -> 4 distinct bank sets
#pragma unroll
      for (int u = 0; u < 8; ++u) {
        float a = sct[u * LSEQ + l];    // 4 distinct addrs/wave, 16-way broadcast
        acc[u].x += a * vv4.x;
        acc[u].y += a * vv4.y;
        acc[u].z += a * vv4.z;
        acc[u].w += a * vv4.w;
      }
    }
    __syncthreads();                    // protect vt4 before next stage
  }

  // reduce partials over lq (lane bits 4,5) — dq position preserved
#pragma unroll
  for (int u = 0; u < 8; ++u) {
    acc[u].x += __shfl_xor(acc[u].x, 16, 64);
    acc[u].y += __shfl_xor(acc[u].y, 16, 64);
    acc[u].z += __shfl_xor(acc[u].z, 16, 64);
    acc[u].w += __shfl_xor(acc[u].w, 16, 64);
    acc[u].x += __shfl_xor(acc[u].x, 32, 64);
    acc[u].y += __shfl_xor(acc[u].y, 32, 64);
    acc[u].z += __shfl_xor(acc[u].z, 32, 64);
    acc[u].w += __shfl_xor(acc[u].w, 32, 64);
  }
  __syncthreads();                      // vt4 free -> reuse as pacc[w][8u][64d] (8KB)
  float* pacc = (float*)vt4;
  if (lq == 0) {
#pragma unroll
    for (int u = 0; u < 8; ++u)
      ((float4*)pacc)[(w * 8 + u) * 16 + dq] = acc[u];
  }
  __syncthreads();
#pragma unroll
  for (int j = 0; j < 2; ++j) {
    int idx = t + 256 * j;
    int uu = idx >> 6, d = idx & 63;
    float s = pacc[(0 * 8 + uu) * 64 + d] + pacc[(1 * 8 + uu) * 64 + d]
            + pacc[(2 * 8 + uu) * 64 + d] + pacc[(3 * 8 + uu) * 64 + d];
    ctx[((size_t)bh * UU + u0 + uu) * DDIM + d] = s;
  }
}

extern "C" void kernel_launch(void* const* d_in, const int* in_sizes, int n_in,
                              void* d_out, int out_size, void* d_ws, size_t ws_size,
                              hipStream_t stream) {
  const float* q   = (const float*)d_in[0];
  const float* k   = (const float*)d_in[1];
  const float* v   = (const float*)d_in[2];
  const int*   idx = (const int*)d_in[3];

  float* ctx  = (float*)d_out;                  // [NBH, UU, DDIM]
  float* attn = (float*)d_out + CTX_ELEMS;      // [NBH, UU, LSEQ]
  // Mpart scratch lives in the attn output region; consumed by k3 BEFORE k457
  // overwrites the region with real attn. NBH*NCHUNK*LSEQ float2 = 4.19M floats
  // < 5.24M available. [proven R2/R4-R9]
  float2* Mpart = (float2*)attn;

  int* sidx  = (int*)d_ws;                       // LSEQ*UU + 16 pad = 81936 ints
  int* soff  = sidx + LSEQ * UU + 16;            // LSEQ*NCHUNK     = 32768 ints
  int* Mtop  = soff + LSEQ * NCHUNK;             // NBH*UU          = 2560 ints

  k0_sort<<<LSEQ / 4, 256, 0, stream>>>(idx, sidx, soff);
  k12_gather<<<512, 512, 0, stream>>>(q, k, sidx, soff, Mpart, 0);
  k12_gather<<<512, 512, 0, stream>>>(q, k, sidx, soff, Mpart, 512);
  k3_topk<<<NBH, 256, 0, stream>>>(Mpart, Mtop);
  k457_fused<<<NBH * 5, 256, 0, stream>>>(q, k, v, Mtop, attn, ctx);
}

// Round 11
// 294.909 us; speedup vs baseline: 1.1571x; 1.1571x over previous
//
#include <hip/hip_runtime.h>
#include <math.h>

// ProbAttention (Informer ProbSparse) — B=8 L=2048 H=8 D=64 u=40
// q/k/v reshape(B,H,L,D) is a flat reinterpretation -> treat as (BH=64, L, D) contiguous.
#define LSEQ 2048
#define DDIM 64
#define UU   40
#define NBH  64
#define NCHUNK 16
#define CROWS  128            // rows per k-chunk (CROWS*NCHUNK == LSEQ)
#define CTX_ELEMS (NBH*UU*DDIM)   // 163840

// 8-lane-group sum via DPP (pure VALU — keeps the LDS pipe free).
__device__ __forceinline__ float grp8_sum(float x) {
  float t;
  t = __int_as_float(__builtin_amdgcn_update_dpp(0, __float_as_int(x), 0xB1, 0xF, 0xF, false));
  x += t;
  t = __int_as_float(__builtin_amdgcn_update_dpp(0, __float_as_int(x), 0x4E, 0xF, 0xF, false));
  x += t;
  t = __int_as_float(__builtin_amdgcn_update_dpp(0, __float_as_int(x), 0x141, 0xF, 0xF, false));
  x += t;
  return x;
}

// ---------------- K0: bin sample indices by 128-row chunk (shared across all bh) ----
// One wave per l. Stable wave-parallel bucket sort via ballot/popcount. [proven R2-R10]
__global__ __launch_bounds__(256) void k0_sort(
    const int* __restrict__ idxs, int* __restrict__ sidx, int* __restrict__ soff) {
  int l = blockIdx.x * 4 + (threadIdx.x >> 6);
  int lane = threadIdx.x & 63;
  int v = 0, c = NCHUNK;              // lanes >= UU get invalid chunk
  if (lane < UU) { v = idxs[l * UU + lane]; c = v >> 7; }   // 128 rows/chunk
  unsigned long long lower = (1ull << lane) - 1ull;
  int base = 0;
#pragma unroll
  for (int cc = 0; cc < NCHUNK; ++cc) {
    unsigned long long m = __ballot(c == cc);
    if (c == cc) {
      int rank = __popcll(m & lower);
      sidx[l * UU + base + rank] = v;
    }
    int cnt = __popcll(m);
    if (lane == cc) soff[l * NCHUNK + cc] = (base << 8) | cnt;
    base += cnt;
  }
}

// ---------------- K12 (R6 form, single launch): LDS-chunk gather, sequential l -----
// 1024 blocks (bh = b&63, c = b>>6), 512 threads (8 waves), 32KB LDS, 4 blocks/CU.
// Proven local optimum: 87us, FETCH 34.7MB, WRITE 18.5MB, dual-pipe ~60% issue.
// R10's 2x512-block split cost ~13us (halved resident blocks/CU) — reverted.
__global__ __launch_bounds__(512, 8) void k12_gather(
    const float* __restrict__ q, const float* __restrict__ k,
    const int* __restrict__ sidx, const int* __restrict__ soff,
    float2* __restrict__ Mpart) {
  __shared__ float4 kt[CROWS * 16];   // 32KB, linear row-major
  int b = blockIdx.x;
  int bh = b & 63;
  int c  = b >> 6;
  int t  = threadIdx.x;

  {
    const float4* src = (const float4*)(k + ((size_t)bh * LSEQ + c * CROWS) * DDIM);
#pragma unroll
    for (int j = 0; j < 4; ++j) kt[t + 512 * j] = src[t + 512 * j];
  }
  __syncthreads();

  int w = t >> 6;            // wave 0..7 owns l in [w*256, w*256+256)
  int lane = t & 63;
  int g = lane >> 3;         // group 0..7 (one l each per batch)
  int sub = lane & 7;

#pragma unroll 1
  for (int lb = 0; lb < 256; lb += 8) {
    int l = w * 256 + lb + g;
    const float4* qr = (const float4*)(q + ((size_t)bh * LSEQ + l) * DDIM);
    float4 qa = qr[sub];        // q row bytes [0,128)
    float4 qb = qr[sub + 8];    // q row bytes [128,256)
    int oc   = soff[l * NCHUNK + c];
    int cnt  = oc & 255;
    int base = oc >> 8;
    const int* sp = sidx + l * UU + base;    // sidx padded +16 -> safe overread
    int rowv[8];
#pragma unroll
    for (int s = 0; s < 8; ++s) rowv[s] = sp[s] & (CROWS - 1);
    float mx = -INFINITY, sm = 0.f;
#pragma unroll
    for (int s = 0; s < 8; ++s) {
      if (__any(s < cnt)) {                  // wave-uniform skip of dead slots
        if (s < cnt) {
          const float4* kr = kt + rowv[s] * 16;
          float4 a  = kr[sub];
          float4 bq = kr[sub + 8];
          float d = qa.x * a.x + qa.y * a.y + qa.z * a.z + qa.w * a.w
                  + qb.x * bq.x + qb.y * bq.y + qb.z * bq.z + qb.w * bq.w;
          d = grp8_sum(d);                    // group-wide: all 8 lanes active
          mx = fmaxf(mx, d);
          sm += d;
        }
      }
    }
    for (int s = 8; s < cnt; ++s) {           // very rare (P(cnt>8) ~ 5e-4)
      int row = sidx[l * UU + base + s] & (CROWS - 1);
      const float4* kr = kt + row * 16;
      float4 a  = kr[sub];
      float4 bq = kr[sub + 8];
      float d = qa.x * a.x + qa.y * a.y + qa.z * a.z + qa.w * a.w
              + qb.x * bq.x + qb.y * bq.y + qb.z * bq.z + qb.w * bq.w;
      d = grp8_sum(d);
      mx = fmaxf(mx, d);
      sm += d;
    }
    if (sub == 0) Mpart[((size_t)bh * NCHUNK + c) * LSEQ + l] = make_float2(mx, sm);
  }
}

// ---------------- K3: top-40 per head; combines 16 Mpart chunks during load --------
// desc value, tie -> smaller index (matches jax.lax.top_k stability)
__global__ __launch_bounds__(256) void k3_topk(const float2* __restrict__ Mp,
                                               int* __restrict__ Mtop) {
  int bh = blockIdx.x;
  int t = threadIdx.x;
  int w = t >> 6;
  int lane = t & 63;
  float v[8];
#pragma unroll
  for (int j = 0; j < 8; ++j) {
    int l = t + 256 * j;
    float mxv = -INFINITY, smv = 0.f;
#pragma unroll
    for (int c = 0; c < NCHUNK; ++c) {
      float2 p = Mp[((size_t)bh * NCHUNK + c) * LSEQ + l];
      mxv = fmaxf(mxv, p.x);
      smv += p.y;
    }
    v[j] = mxv - smv * (1.0f / (float)LSEQ);
  }
  __shared__ float swv[4];
  __shared__ int   swi[4];
  __shared__ int   win;
  for (int it = 0; it < UU; ++it) {
    float bv = -INFINITY; int bi = 0x7fffffff;
#pragma unroll
    for (int j = 0; j < 8; ++j) {
      if (v[j] > bv) { bv = v[j]; bi = t + 256 * j; }
    }
#pragma unroll
    for (int off = 32; off > 0; off >>= 1) {
      float ov = __shfl_xor(bv, off, 64);
      int   oi = __shfl_xor(bi, off, 64);
      if (ov > bv || (ov == bv && oi < bi)) { bv = ov; bi = oi; }
    }
    if (lane == 0) { swv[w] = bv; swi[w] = bi; }
    __syncthreads();
    if (t == 0) {
      float fv = swv[0]; int fi = swi[0];
#pragma unroll
      for (int j = 1; j < 4; ++j) {
        if (swv[j] > fv || (swv[j] == fv && swi[j] < fi)) { fv = swv[j]; fi = swi[j]; }
      }
      Mtop[bh * UU + it] = fi;
      win = fi;
    }
    __syncthreads();
    int wi = win;
#pragma unroll
    for (int j = 0; j < 8; ++j)
      if (wi == t + 256 * j) v[j] = -INFINITY;   // static index, predicated
  }
}

// ---------------- K457 v3: 4 u per block, 512 THREADS — occupancy fix --------------
// R10 measured v2 (8u, 320 blocks) at 90us / 13.5% occupancy: grid < 2 blocks/CU is
// the poison, and the kernel was never BW-bound (607 GB/s). v3 keeps the proven 4-u
// 640-block grid (2.5 blocks/CU) and doubles waves per block: 512 thr, LDS 48KB
// (sct 32K + vt 16K) -> 3 blocks/CU cap -> ~20 waves/CU (~62%) vs R5's ~10.
// Phase A: DPP 8-lane geometry (k row read once per 4 dots, zero shfl).
// Softmax: row r = w&3 split across wave pair (w, w+4) by l-half; 2-barrier combine
// via LDS partials (keeps VGPR <= 85 for __launch_bounds__(512,6)).
// Phase B: R5-proven swizzled v-tile; wave w owns 8 rows/tile; acc[4]x float4.
__global__ __launch_bounds__(512, 6) void k457_fused(
    const float* __restrict__ q, const float* __restrict__ k,
    const float* __restrict__ v, const int* __restrict__ Mtop,
    float* __restrict__ attn, float* __restrict__ ctx) {
  __shared__ float  sct[4 * LSEQ];     // 32KB, [u][l]: scores -> normalized attn
  __shared__ float4 vt4[64 * 16];      // 16KB v tile (swizzled); reused: sm-partials, pacc
  int b = blockIdx.x;
  int bh = b & 63;
  int u0 = (b >> 6) * 4;
  int t = threadIdx.x;
  int w = t >> 6, lane = t & 63;

  // ---- phase A: scores, 8-lane-group + DPP; 512 thr cover 64 l per iteration ----
  {
    int g = t >> 3;          // 0..63: l-row within stripe (wave w owns g in [w*8,w*8+8))
    int sub = t & 7;
    float4 qa[4], qb[4];
#pragma unroll
    for (int u = 0; u < 4; ++u) {
      int qi = Mtop[bh * UU + u0 + u];
      const float4* qr = (const float4*)(q + (size_t)(bh * LSEQ + qi) * DDIM);
      qa[u] = qr[sub];         // q row bytes [0,128)
      qb[u] = qr[sub + 8];     // bytes [128,256)
    }
    const float* kb = k + (size_t)bh * LSEQ * DDIM;
#pragma unroll 1
    for (int p = 0; p < 32; ++p) {
      int l = p * 64 + g;
      const float4* kr = (const float4*)(kb + (size_t)l * DDIM);
      float4 ka = kr[sub];     // wave reads 8 consecutive rows x 256B -> coalesced
      float4 kc = kr[sub + 8];
#pragma unroll
      for (int u = 0; u < 4; ++u) {
        float s = qa[u].x * ka.x + qa[u].y * ka.y + qa[u].z * ka.z + qa[u].w * ka.w
                + qb[u].x * kc.x + qb[u].y * kc.y + qb[u].z * kc.z + qb[u].w * kc.w;
        s = grp8_sum(s);
        if (sub == 0) sct[u * LSEQ + l] = s * 0.125f;   // banks l%32: conflict-free
      }
    }
  }
  __syncthreads();

  // ---- softmax: row r = w&3, wave-pair (w, w+4) split the 2048 row by halves ----
  {
    int r = w & 3, h = w >> 2;            // h = l-half this wave owns
    float* row = sct + r * LSEQ + h * 1024;
    float* sred = (float*)vt4;            // [0..7]=max[h][r], [8..15]=sum[h][r]
    float vv[16];
    float mx = -INFINITY;
#pragma unroll
    for (int j = 0; j < 16; ++j) { vv[j] = row[lane + 64 * j]; mx = fmaxf(mx, vv[j]); }
#pragma unroll
    for (int off = 32; off > 0; off >>= 1) mx = fmaxf(mx, __shfl_xor(mx, off, 64));
    if (lane == 0) sred[h * 4 + r] = mx;
    __syncthreads();
    mx = fmaxf(sred[r], sred[4 + r]);     // combine halves
    float sm = 0.f;
#pragma unroll
    for (int j = 0; j < 16; ++j) { vv[j] = __expf(vv[j] - mx); sm += vv[j]; }
#pragma unroll
    for (int off = 32; off > 0; off >>= 1) sm += __shfl_xor(sm, off, 64);
    if (lane == 0) sred[8 + h * 4 + r] = sm;
    __syncthreads();
    sm = sred[8 + r] + sred[12 + r];
    float inv = 1.0f / sm;
    float* ap = attn + (size_t)(bh * UU + u0 + r) * LSEQ + h * 1024;
#pragma unroll
    for (int j = 0; j < 16; ++j) {
      float a = vv[j] * inv;
      row[lane + 64 * j] = a;
      ap[lane + 64 * j] = a;
    }
  }
  __syncthreads();

  // ---- phase B: ctx[bh, u0+u, :] = sum_l attn[u][l] * v[bh, l, :] ----
  int dq = lane & 15;        // d-quad: d = dq*4 .. dq*4+3
  int lq = lane >> 4;        // row-slice 0..3
  float4 acc[4];
#pragma unroll
  for (int u = 0; u < 4; ++u) acc[u] = make_float4(0.f, 0.f, 0.f, 0.f);

  const float4* vsrc = (const float4*)(v + (size_t)bh * LSEQ * DDIM);
#pragma unroll 1
  for (int tile = 0; tile < 32; ++tile) {
    // stage 64 v rows (1024 float4 / 512 thr = 2 each), slot swizzle c4 ^ (row&3)
#pragma unroll
    for (int i = 0; i < 2; ++i) {
      int idx = t + 512 * i;            // float4 index in tile (0..1023)
      int row = idx >> 4, c4 = idx & 15;
      vt4[row * 16 + (c4 ^ (row & 3))] = vsrc[tile * 1024 + idx];
    }
    __syncthreads();
#pragma unroll
    for (int i = 0; i < 2; ++i) {
      int r = w * 8 + i * 4 + lq;       // wave w owns rows [w*8, w*8+8) of tile
      int l = tile * 64 + r;
      float4 vv4 = vt4[r * 16 + (dq ^ (r & 3))];   // 4 lq -> 4 distinct bank sets
#pragma unroll
      for (int u = 0; u < 4; ++u) {
        float a = sct[u * LSEQ + l];    // 4 distinct addrs/wave, 16-way broadcast
        acc[u].x += a * vv4.x;
        acc[u].y += a * vv4.y;
        acc[u].z += a * vv4.z;
        acc[u].w += a * vv4.w;
      }
    }
    __syncthreads();                    // protect vt4 before next stage
  }

  // reduce partials over lq (lane bits 4,5) — dq position preserved
#pragma unroll
  for (int u = 0; u < 4; ++u) {
    acc[u].x += __shfl_xor(acc[u].x, 16, 64);
    acc[u].y += __shfl_xor(acc[u].y, 16, 64);
    acc[u].z += __shfl_xor(acc[u].z, 16, 64);
    acc[u].w += __shfl_xor(acc[u].w, 16, 64);
    acc[u].x += __shfl_xor(acc[u].x, 32, 64);
    acc[u].y += __shfl_xor(acc[u].y, 32, 64);
    acc[u].z += __shfl_xor(acc[u].z, 32, 64);
    acc[u].w += __shfl_xor(acc[u].w, 32, 64);
  }
  __syncthreads();                      // vt4 free -> reuse as pacc[8w][4u][64d] (8KB)
  float* pacc = (float*)vt4;
  if (lq == 0) {
#pragma unroll
    for (int u = 0; u < 4; ++u)
      ((float4*)pacc)[(w * 4 + u) * 16 + dq] = acc[u];
  }
  __syncthreads();
  if (t < 256) {
    int uu = t >> 6, d = t & 63;
    float s = 0.f;
#pragma unroll
    for (int ww = 0; ww < 8; ++ww) s += pacc[(ww * 4 + uu) * 64 + d];
    ctx[((size_t)bh * UU + u0 + uu) * DDIM + d] = s;
  }
}

extern "C" void kernel_launch(void* const* d_in, const int* in_sizes, int n_in,
                              void* d_out, int out_size, void* d_ws, size_t ws_size,
                              hipStream_t stream) {
  const float* q   = (const float*)d_in[0];
  const float* k   = (const float*)d_in[1];
  const float* v   = (const float*)d_in[2];
  const int*   idx = (const int*)d_in[3];

  float* ctx  = (float*)d_out;                  // [NBH, UU, DDIM]
  float* attn = (float*)d_out + CTX_ELEMS;      // [NBH, UU, LSEQ]
  // Mpart scratch lives in the attn output region; consumed by k3 BEFORE k457
  // overwrites the region with real attn. NBH*NCHUNK*LSEQ float2 = 4.19M floats
  // < 5.24M available. [proven R2/R4-R10]
  float2* Mpart = (float2*)attn;

  int* sidx  = (int*)d_ws;                       // LSEQ*UU + 16 pad = 81936 ints
  int* soff  = sidx + LSEQ * UU + 16;            // LSEQ*NCHUNK     = 32768 ints
  int* Mtop  = soff + LSEQ * NCHUNK;             // NBH*UU          = 2560 ints

  k0_sort<<<LSEQ / 4, 256, 0, stream>>>(idx, sidx, soff);
  k12_gather<<<NBH * NCHUNK, 512, 0, stream>>>(q, k, sidx, soff, Mpart);
  k3_topk<<<NBH, 256, 0, stream>>>(Mpart, Mtop);
  k457_fused<<<NBH * 10, 512, 0, stream>>>(q, k, v, Mtop, attn, ctx);
}